// Round 1
// baseline (370.397 us; speedup 1.0000x reference)
//
#include <hip/hip_runtime.h>
#include <math.h>

// ---------------------------------------------------------------------------
// RPNet: box->xyxy, ROI adaptive max pool (3 levels, fused), split-K matmul
// hid = rois @ Wh[k] + bh, fused reduce+heads, output [16, 242] f32.
//
// ws layout (floats):
//   rois    at 0         : 16 * 53248       = 3,407,872
//   partial at 3,407,872 : 7 * 104 * 16*128 = 1,490,944
// total 4,898,816 floats = 19.6 MB (unchanged from baseline)
// ---------------------------------------------------------------------------

#define B 16
#define F_TOT 53248
#define FC 512               // f-chunk per matmul block
#define NCHUNK (F_TOT / FC)  // 104

__device__ __forceinline__ float clamp01(float v) {
    return fminf(fmaxf(v, 0.0f), 1.0f);
}

// Fused 3-level ROI adaptive max pool. One thread per output bin (b,c,i,j).
// blocks 0..511 -> x2 (C=64,S=128), 512..1791 -> x4 (C=160,S=64),
// 1792..3327 -> x6 (C=192,S=32).  (unchanged from baseline)
__global__ __launch_bounds__(256) void roi_all(const float* __restrict__ x2,
                                               const float* __restrict__ x4,
                                               const float* __restrict__ x6,
                                               const float* __restrict__ box,
                                               float* __restrict__ rois) {
    const int blk = blockIdx.x;
    const float* feat;
    int C, S, fbase, t;
    if (blk < 512)       { feat = x2; C = 64;  S = 128; fbase = 0;     t = blk * 256 + threadIdx.x; }
    else if (blk < 1792) { feat = x4; C = 160; S = 64;  fbase = 8192;  t = (blk - 512) * 256 + threadIdx.x; }
    else                 { feat = x6; C = 192; S = 32;  fbase = 28672; t = (blk - 1792) * 256 + threadIdx.x; }

    int j = t & 7;
    int i = (t >> 3) & 15;
    int c = (t >> 7) % C;
    int b = t / (C << 7);

    const float* bx = box + b * 4;
    float x = bx[0], y = bx[1], wd = bx[2], ht = bx[3];
    float Sf = (float)S;
    // bit-exact vs np: 0.5*w exact (pow2), fma(x -/+ 0.5w) single-round equals
    // np's x + (-0.5w) since the product is exact; *2^k exact; trunc>=0==floor
    int x1 = (int)(clamp01(x - 0.5f * wd) * Sf);
    int y1 = (int)(clamp01(y - 0.5f * ht) * Sf);
    int x2i = (int)(clamp01(x + 0.5f * wd) * Sf);
    int y2i = (int)(clamp01(y + 0.5f * ht) * Sf);
    x2i = min(x2i, S - 1);
    y2i = min(y2i, S - 1);
    int h = y2i - y1 + 1;
    int w = x2i - x1 + 1;

    int rs = y1 + (i * h) / 16;
    int re = y1 + ((i + 1) * h + 15) / 16;   // ceil
    int cs = x1 + (j * w) / 8;
    int ce = x1 + ((j + 1) * w + 7) / 8;     // ceil

    const float* fp = feat + ((size_t)(b * C + c)) * S * S;
    float m = -INFINITY;
    for (int r = rs; r < re; ++r) {
        const float* row = fp + r * S;
        for (int cc = cs; cc < ce; ++cc) m = fmaxf(m, row[cc]);
    }
    int f = fbase + (c * 16 + i) * 8 + j;
    rois[(size_t)b * F_TOT + f] = m;
}

// grid (NCHUNK, 7); block 256 = 4 waves. Lane layout: half = lane>>5 picks one
// of 2 f-rows per load, h0 = (lane&31)*4 -> float4 of h-cols. A wave load is
// 1 KB contiguous (two full 512 B f-rows of Wh). Wave w owns fl = 2w+half (mod 8),
// stepping by 8: 64 iterations, 4x fewer global-load instrs than the float2
// version and 2x the in-flight bytes at the same unroll depth.
__global__ __launch_bounds__(256) void matmul_part(const float* __restrict__ rois,
                                                   const float* __restrict__ Wh,
                                                   float* __restrict__ partial) {
    __shared__ float rs_[FC * 16];   // [f_local][b] layout, 32 KB (reused for reduce)
    const int cid = blockIdx.x;
    const int k = blockIdx.y;
    const int f0 = cid * FC;
    const int tid = threadIdx.x;

    // stage rois chunk
    for (int idx = tid; idx < FC * 16; idx += 256) {
        int b = idx & 15;
        int fl = idx >> 4;
        rs_[idx] = rois[(size_t)b * F_TOT + f0 + fl];
    }
    __syncthreads();

    const int w    = tid >> 6;          // wave 0..3
    const int l    = tid & 63;
    const int half = l >> 5;            // which of 2 f-rows this lane loads
    const int h0   = (l & 31) * 4;      // 4 h columns per lane

    const float* wp = Wh + ((size_t)k * F_TOT + f0 + 2 * w + half) * 128 + h0;
    int fb = ((2 * w + half) << 4);     // rs_ float offset = fl*16

    float4 acc[16];
#pragma unroll
    for (int b = 0; b < 16; ++b) acc[b] = make_float4(0.f, 0.f, 0.f, 0.f);

#pragma unroll 4
    for (int it = 0; it < FC / 8; ++it) {
        const float4 wv = *(const float4*)wp;
        wp += 8 * 128;                  // 8 f-rows ahead
        const float* rp = rs_ + fb;
        fb += 128;                      // 8 fl * 16 b
#pragma unroll
        for (int q = 0; q < 4; ++q) {
            const float4 rv = *(const float4*)(rp + q * 4);
            acc[q*4+0].x += rv.x * wv.x; acc[q*4+0].y += rv.x * wv.y;
            acc[q*4+0].z += rv.x * wv.z; acc[q*4+0].w += rv.x * wv.w;
            acc[q*4+1].x += rv.y * wv.x; acc[q*4+1].y += rv.y * wv.y;
            acc[q*4+1].z += rv.y * wv.z; acc[q*4+1].w += rv.y * wv.w;
            acc[q*4+2].x += rv.z * wv.x; acc[q*4+2].y += rv.z * wv.y;
            acc[q*4+2].z += rv.z * wv.z; acc[q*4+2].w += rv.z * wv.w;
            acc[q*4+3].x += rv.w * wv.x; acc[q*4+3].y += rv.w * wv.y;
            acc[q*4+3].z += rv.w * wv.z; acc[q*4+3].w += rv.w * wv.w;
        }
    }

    // Reduce 8 partials (4 waves x 2 halves) -> partial[k][cid][b][h].
    // Round A: half0 lanes write; Round B: half1 lanes RMW-add; Round C: sum 4 waves.
    __syncthreads();                    // everyone done reading rs_
    float* red = rs_;                   // reuse 8192 floats = [w][b*128+h]
    if (half == 0) {
#pragma unroll
        for (int b = 0; b < 16; ++b)
            *(float4*)(red + w * 2048 + b * 128 + h0) = acc[b];
    }
    __syncthreads();
    if (half == 1) {
#pragma unroll
        for (int b = 0; b < 16; ++b) {
            float4* p = (float4*)(red + w * 2048 + b * 128 + h0);
            float4 t = *p;
            t.x += acc[b].x; t.y += acc[b].y; t.z += acc[b].z; t.w += acc[b].w;
            *p = t;
        }
    }
    __syncthreads();

    float* op = partial + ((size_t)(k * NCHUNK + cid)) * (B * 128);
    for (int idx = tid; idx < 2048; idx += 256) {
        op[idx] = red[idx] + red[idx + 2048] + red[idx + 4096] + red[idx + 6144];
    }
}

// Fused split-K reduce + bias + per-k head. One block per (k, b): 112 blocks.
// k=0 -> o1 (38 outs) + box passthrough; k=1 -> o2 (25); k=2..6 -> od[k-2] (35).
// All out columns are disjoint across k, so blocks write independently.
__global__ __launch_bounds__(512) void tail_kernel(const float* __restrict__ partial,
                                                   const float* __restrict__ bh,
                                                   const float* __restrict__ box,
                                                   const float* __restrict__ Wp, const float* __restrict__ bp,
                                                   const float* __restrict__ Wa, const float* __restrict__ ba,
                                                   const float* __restrict__ Wd, const float* __restrict__ bd,
                                                   float* __restrict__ out) {
    __shared__ float red[512];
    __shared__ float hs[128];
    const int k = blockIdx.x >> 4;
    const int b = blockIdx.x & 15;
    const int tid = threadIdx.x;

    // --- split-K reduce: thread (h, q) sums cids q*26 .. q*26+25 ---
    {
        const int h = tid & 127;
        const int q = tid >> 7;         // 0..3
        const float* pp = partial + (size_t)k * NCHUNK * (B * 128) + b * 128 + h
                        + (size_t)(q * 26) * (B * 128);
        float s = 0.f;
#pragma unroll
        for (int cid = 0; cid < 26; ++cid) s += pp[(size_t)cid * (B * 128)];
        red[tid] = s;
    }
    __syncthreads();
    if (tid < 128) {
        hs[tid] = red[tid] + red[tid + 128] + red[tid + 256] + red[tid + 384]
                + bh[k * 128 + tid];
    }
    __syncthreads();

    // --- head for this k: out_o = bias_o + dot(hs, W[:,o]) ---
    // thread = o*8 + p; lane-group p sums h = p*16 .. p*16+15, xor-tree over 8.
    const int o = tid >> 3;
    const int p = tid & 7;
    const int n_out = (k == 0) ? 38 : (k == 1) ? 25 : 35;
    float v = 0.f;
    if (o < n_out) {
        const float* Wc;
        int ld;
        if (k == 0)      { Wc = Wp; ld = 38; }
        else if (k == 1) { Wc = Wa; ld = 25; }
        else             { Wc = Wd + (size_t)(k - 2) * 128 * 35; ld = 35; }
        const int hbase = p * 16;
#pragma unroll
        for (int hh = 0; hh < 16; ++hh) {
            const int h = hbase + hh;
            v += hs[h] * Wc[h * ld + o];
        }
    }
    v += __shfl_xor(v, 1, 8);
    v += __shfl_xor(v, 2, 8);
    v += __shfl_xor(v, 4, 8);
    if (p == 0 && o < n_out) {
        float bias;
        int off;
        if (k == 0)      { bias = bp[o]; off = 4 + o; }
        else if (k == 1) { bias = ba[o]; off = 42 + o; }
        else             { bias = bd[(k - 2) * 35 + o]; off = 67 + (k - 2) * 35 + o; }
        out[b * 242 + off] = bias + v;
    }
    if (k == 0 && tid >= 504) {
        const int j = tid - 504;
        if (j < 4) out[b * 242 + j] = box[b * 4 + j];
    }
}

extern "C" void kernel_launch(void* const* d_in, const int* in_sizes, int n_in,
                              void* d_out, int out_size, void* d_ws, size_t ws_size,
                              hipStream_t stream) {
    const float* box = (const float*)d_in[0];
    const float* x2  = (const float*)d_in[1];
    const float* x4  = (const float*)d_in[2];
    const float* x6  = (const float*)d_in[3];
    const float* Wh  = (const float*)d_in[4];
    const float* bh  = (const float*)d_in[5];
    const float* Wp  = (const float*)d_in[6];
    const float* bp  = (const float*)d_in[7];
    const float* Wa  = (const float*)d_in[8];
    const float* ba  = (const float*)d_in[9];
    const float* Wd  = (const float*)d_in[10];
    const float* bd  = (const float*)d_in[11];
    float* out = (float*)d_out;

    float* ws = (float*)d_ws;
    float* rois    = ws;                      // 3,407,872 f
    float* partial = ws + (size_t)B * F_TOT;  // 1,490,944 f

    roi_all<<<3328, 256, 0, stream>>>(x2, x4, x6, box, rois);
    matmul_part<<<dim3(NCHUNK, 7), 256, 0, stream>>>(rois, Wh, partial);
    tail_kernel<<<112, 512, 0, stream>>>(partial, bh, box, Wp, bp, Wa, ba, Wd, bd, out);
}

// Round 4
// 353.315 us; speedup vs baseline: 1.0483x; 1.0483x over previous
//
#include <hip/hip_runtime.h>
#include <math.h>

// ---------------------------------------------------------------------------
// RPNet: box->xyxy, ROI adaptive max pool (3 levels, fused), split-K matmul
// hid = rois @ Wh[k] + bh, fused reduce+heads, output [16, 242] f32.
//
// ws layout (floats):
//   rois    at 0         : 53248 * 16 (F-MAJOR [f][b]) = 3,407,872
//   partial at 3,407,872 : 7 * 104 * 16*128            = 1,490,944
// total 4,898,816 floats = 19.6 MB
// ---------------------------------------------------------------------------

#define B 16
#define F_TOT 53248
#define FC 512               // f-chunk per matmul block
#define NCHUNK (F_TOT / FC)  // 104

// clang-native 4-float vector: required by __builtin_nontemporal_load
// (HIP's float4 is a class type the builtin rejects).
typedef float vf4 __attribute__((ext_vector_type(4)));

__device__ __forceinline__ float clamp01(float v) {
    return fminf(fmaxf(v, 0.0f), 1.0f);
}

// Fused 3-level ROI adaptive max pool. One thread per output bin (b,c,i,j),
// with b in the low 4 bits of the thread index so the f-major store
// rois[f*16+b] == rois[t] is fully coalesced.
// blocks 0..511 -> x2 (C=64,S=128), 512..1791 -> x4 (C=160,S=64),
// 1792..3327 -> x6 (C=192,S=32).
__global__ __launch_bounds__(256) void roi_all(const float* __restrict__ x2,
                                               const float* __restrict__ x4,
                                               const float* __restrict__ x6,
                                               const float* __restrict__ box,
                                               float* __restrict__ rois) {
    const int blk = blockIdx.x;
    const float* feat;
    int C, S, fbase, t;
    if (blk < 512)       { feat = x2; C = 64;  S = 128; fbase = 0;     t = blk * 256 + threadIdx.x; }
    else if (blk < 1792) { feat = x4; C = 160; S = 64;  fbase = 8192;  t = (blk - 512) * 256 + threadIdx.x; }
    else                 { feat = x6; C = 192; S = 32;  fbase = 28672; t = (blk - 1792) * 256 + threadIdx.x; }

    const int b = t & 15;        // lane-fastest: coalesced f-major store
    const int f = t >> 4;        // f = c*128 + i*8 + j
    const int j = f & 7;
    const int i = (f >> 3) & 15;
    const int c = f >> 7;

    const float* bx = box + b * 4;
    float x = bx[0], y = bx[1], wd = bx[2], ht = bx[3];
    float Sf = (float)S;
    // bit-exact vs np: 0.5*w exact (pow2), fma(x -/+ 0.5w) single-round equals
    // np's x + (-0.5w) since the product is exact; *2^k exact; trunc>=0==floor
    int x1 = (int)(clamp01(x - 0.5f * wd) * Sf);
    int y1 = (int)(clamp01(y - 0.5f * ht) * Sf);
    int x2i = (int)(clamp01(x + 0.5f * wd) * Sf);
    int y2i = (int)(clamp01(y + 0.5f * ht) * Sf);
    x2i = min(x2i, S - 1);
    y2i = min(y2i, S - 1);
    int h = y2i - y1 + 1;
    int w = x2i - x1 + 1;

    int rs = y1 + (i * h) / 16;
    int re = y1 + ((i + 1) * h + 15) / 16;   // ceil
    int cs = x1 + (j * w) / 8;
    int ce = x1 + ((j + 1) * w + 7) / 8;     // ceil

    const float* fp = feat + ((size_t)(b * C + c)) * S * S;
    float m = -INFINITY;
    for (int r = rs; r < re; ++r) {
        const float* row = fp + r * S;
        int cc = cs;
        // 4-wide: independent loads -> 4x memory-level parallelism on the
        // serial fmax chain (dominant cost at S=128 where bins reach 9x17).
        for (; cc + 3 < ce; cc += 4) {
            float a0 = row[cc + 0];
            float a1 = row[cc + 1];
            float a2 = row[cc + 2];
            float a3 = row[cc + 3];
            m = fmaxf(m, fmaxf(fmaxf(a0, a1), fmaxf(a2, a3)));
        }
        for (; cc < ce; ++cc) m = fmaxf(m, row[cc]);
    }
    rois[(size_t)blk * 256 + threadIdx.x] = m;   // == rois[f*16 + b]
}

// grid (NCHUNK, 7); block 256 = 4 waves. Lane layout: half = lane>>5 picks one
// of 2 f-rows per load, h0 = (lane&31)*4 -> float4 of h-cols. A wave load is
// 1 KB contiguous (two full 512 B f-rows of Wh). With f-major rois, staging is
// a contiguous 32 KB float4 block copy (was 8192 scattered scalar loads).
__global__ __launch_bounds__(256) void matmul_part(const float* __restrict__ rois,
                                                   const float* __restrict__ Wh,
                                                   float* __restrict__ partial) {
    __shared__ float rs_[FC * 16];   // [f_local][b] layout, 32 KB (reused for reduce)
    const int cid = blockIdx.x;
    const int k = blockIdx.y;
    const int f0 = cid * FC;
    const int tid = threadIdx.x;

    // stage rois chunk: contiguous copy, coalesced float4 both sides
    {
        const float4* src = (const float4*)(rois + (size_t)f0 * 16);
        float4* dst = (float4*)rs_;
        for (int idx = tid; idx < FC * 16 / 4; idx += 256) dst[idx] = src[idx];
    }
    __syncthreads();

    const int w    = tid >> 6;          // wave 0..3
    const int l    = tid & 63;
    const int half = l >> 5;            // which of 2 f-rows this lane loads
    const int h0   = (l & 31) * 4;      // 4 h columns per lane

    const float* wp = Wh + ((size_t)k * F_TOT + f0 + 2 * w + half) * 128 + h0;
    int fb = ((2 * w + half) << 4);     // rs_ float offset = fl*16

    float4 acc[16];
#pragma unroll
    for (int b = 0; b < 16; ++b) acc[b] = make_float4(0.f, 0.f, 0.f, 0.f);

#pragma unroll 4
    for (int it = 0; it < FC / 8; ++it) {
        const vf4 wv = __builtin_nontemporal_load((const vf4*)wp);
        wp += 8 * 128;                  // 8 f-rows ahead
        const float* rp = rs_ + fb;
        fb += 128;                      // 8 fl * 16 b
#pragma unroll
        for (int q = 0; q < 4; ++q) {
            const float4 rv = *(const float4*)(rp + q * 4);
            acc[q*4+0].x += rv.x * wv.x; acc[q*4+0].y += rv.x * wv.y;
            acc[q*4+0].z += rv.x * wv.z; acc[q*4+0].w += rv.x * wv.w;
            acc[q*4+1].x += rv.y * wv.x; acc[q*4+1].y += rv.y * wv.y;
            acc[q*4+1].z += rv.y * wv.z; acc[q*4+1].w += rv.y * wv.w;
            acc[q*4+2].x += rv.z * wv.x; acc[q*4+2].y += rv.z * wv.y;
            acc[q*4+2].z += rv.z * wv.z; acc[q*4+2].w += rv.z * wv.w;
            acc[q*4+3].x += rv.w * wv.x; acc[q*4+3].y += rv.w * wv.y;
            acc[q*4+3].z += rv.w * wv.z; acc[q*4+3].w += rv.w * wv.w;
        }
    }

    // Reduce 8 partials (4 waves x 2 halves) -> partial[k][cid][b][h].
    // Round A: half0 lanes write; Round B: half1 lanes RMW-add; Round C: sum 4 waves.
    __syncthreads();                    // everyone done reading rs_
    float* red = rs_;                   // reuse 8192 floats = [w][b*128+h]
    if (half == 0) {
#pragma unroll
        for (int b = 0; b < 16; ++b)
            *(float4*)(red + w * 2048 + b * 128 + h0) = acc[b];
    }
    __syncthreads();
    if (half == 1) {
#pragma unroll
        for (int b = 0; b < 16; ++b) {
            float4* p = (float4*)(red + w * 2048 + b * 128 + h0);
            float4 t = *p;
            t.x += acc[b].x; t.y += acc[b].y; t.z += acc[b].z; t.w += acc[b].w;
            *p = t;
        }
    }
    __syncthreads();

    float* op = partial + ((size_t)(k * NCHUNK + cid)) * (B * 128);
    for (int idx = tid; idx < 2048; idx += 256) {
        op[idx] = red[idx] + red[idx + 2048] + red[idx + 4096] + red[idx + 6144];
    }
}

// Fused split-K reduce + bias + per-k head. One block per (k, b): 112 blocks.
// k=0 -> o1 (38 outs) + box passthrough; k=1 -> o2 (25); k=2..6 -> od[k-2] (35).
// All out columns are disjoint across k, so blocks write independently.
__global__ __launch_bounds__(512) void tail_kernel(const float* __restrict__ partial,
                                                   const float* __restrict__ bh,
                                                   const float* __restrict__ box,
                                                   const float* __restrict__ Wp, const float* __restrict__ bp,
                                                   const float* __restrict__ Wa, const float* __restrict__ ba,
                                                   const float* __restrict__ Wd, const float* __restrict__ bd,
                                                   float* __restrict__ out) {
    __shared__ float red[512];
    __shared__ float hs[128];
    const int k = blockIdx.x >> 4;
    const int b = blockIdx.x & 15;
    const int tid = threadIdx.x;

    // --- split-K reduce: thread (h, q) sums cids q*26 .. q*26+25 ---
    {
        const int h = tid & 127;
        const int q = tid >> 7;         // 0..3
        const float* pp = partial + (size_t)k * NCHUNK * (B * 128) + b * 128 + h
                        + (size_t)(q * 26) * (B * 128);
        float s = 0.f;
#pragma unroll
        for (int cid = 0; cid < 26; ++cid) s += pp[(size_t)cid * (B * 128)];
        red[tid] = s;
    }
    __syncthreads();
    if (tid < 128) {
        hs[tid] = red[tid] + red[tid + 128] + red[tid + 256] + red[tid + 384]
                + bh[k * 128 + tid];
    }
    __syncthreads();

    // --- head for this k: out_o = bias_o + dot(hs, W[:,o]) ---
    // thread = o*8 + p; lane-group p sums h = p*16 .. p*16+15, xor-tree over 8.
    const int o = tid >> 3;
    const int p = tid & 7;
    const int n_out = (k == 0) ? 38 : (k == 1) ? 25 : 35;
    float v = 0.f;
    if (o < n_out) {
        const float* Wc;
        int ld;
        if (k == 0)      { Wc = Wp; ld = 38; }
        else if (k == 1) { Wc = Wa; ld = 25; }
        else             { Wc = Wd + (size_t)(k - 2) * 128 * 35; ld = 35; }
        const int hbase = p * 16;
#pragma unroll
        for (int hh = 0; hh < 16; ++hh) {
            const int h = hbase + hh;
            v += hs[h] * Wc[h * ld + o];
        }
    }
    v += __shfl_xor(v, 1, 8);
    v += __shfl_xor(v, 2, 8);
    v += __shfl_xor(v, 4, 8);
    if (p == 0 && o < n_out) {
        float bias;
        int off;
        if (k == 0)      { bias = bp[o]; off = 4 + o; }
        else if (k == 1) { bias = ba[o]; off = 42 + o; }
        else             { bias = bd[(k - 2) * 35 + o]; off = 67 + (k - 2) * 35 + o; }
        out[b * 242 + off] = bias + v;
    }
    if (k == 0 && tid >= 504) {
        const int j = tid - 504;
        if (j < 4) out[b * 242 + j] = box[b * 4 + j];
    }
}

extern "C" void kernel_launch(void* const* d_in, const int* in_sizes, int n_in,
                              void* d_out, int out_size, void* d_ws, size_t ws_size,
                              hipStream_t stream) {
    const float* box = (const float*)d_in[0];
    const float* x2  = (const float*)d_in[1];
    const float* x4  = (const float*)d_in[2];
    const float* x6  = (const float*)d_in[3];
    const float* Wh  = (const float*)d_in[4];
    const float* bh  = (const float*)d_in[5];
    const float* Wp  = (const float*)d_in[6];
    const float* bp  = (const float*)d_in[7];
    const float* Wa  = (const float*)d_in[8];
    const float* ba  = (const float*)d_in[9];
    const float* Wd  = (const float*)d_in[10];
    const float* bd  = (const float*)d_in[11];
    float* out = (float*)d_out;

    float* ws = (float*)d_ws;
    float* rois    = ws;                      // 3,407,872 f  ([f][b] F-MAJOR)
    float* partial = ws + (size_t)B * F_TOT;  // 1,490,944 f
    (void)ws_size;

    roi_all<<<3328, 256, 0, stream>>>(x2, x4, x6, box, rois);
    matmul_part<<<dim3(NCHUNK, 7), 256, 0, stream>>>(rois, Wh, partial);
    tail_kernel<<<112, 512, 0, stream>>>(partial, bh, box, Wp, bp, Wa, ba, Wd, bd, out);
}

// Round 5
// 350.921 us; speedup vs baseline: 1.0555x; 1.0068x over previous
//
#include <hip/hip_runtime.h>
#include <math.h>

// ---------------------------------------------------------------------------
// RPNet: box->xyxy, ROI adaptive max pool (3 levels, fused), split-K matmul
// hid = rois @ Wh[k] + bh, fused reduce+heads, output [16, 242] f32.
//
// ws layout (floats):
//   rois    at 0         : 53248 * 16 (F-MAJOR [f][b]) = 3,407,872
//   partial at 3,407,872 : 7 * 104 * 16*128            = 1,490,944
// total 4,898,816 floats = 19.6 MB
// ---------------------------------------------------------------------------

#define B 16
#define F_TOT 53248
#define FC 512               // f-chunk per matmul block
#define NCHUNK (F_TOT / FC)  // 104

// clang-native 4-float vector: required by __builtin_nontemporal_load
// (HIP's float4 is a class type the builtin rejects).
typedef float vf4 __attribute__((ext_vector_type(4)));

__device__ __forceinline__ float clamp01(float v) {
    return fminf(fmaxf(v, 0.0f), 1.0f);
}

// Fused 3-level ROI adaptive max pool.
// Wave-uniform mapping: each (b,c) channel-pair owns 128 consecutive threads
// (2 waves), bin = tid&127 -> i = bin>>3, j = bin&7. All lanes of a wave share
// one ROI -> loop bounds uniform to +-1 (no 16-way b divergence), and an
// i-group's 8 lanes read adjacent column ranges of the same rows (coalesced-ish,
// L1-resident channel region). Store stays f-major for matmul staging.
// blocks 0..511 -> x2 (C=64,S=128), 512..1791 -> x4 (C=160,S=64),
// 1792..3327 -> x6 (C=192,S=32).  Grid unchanged: 2 pairs per 256-thr block.
__global__ __launch_bounds__(256) void roi_all(const float* __restrict__ x2,
                                               const float* __restrict__ x4,
                                               const float* __restrict__ x6,
                                               const float* __restrict__ box,
                                               float* __restrict__ rois) {
    const int blk = blockIdx.x;
    const float* feat;
    int C, S, fbase, pair0;
    if (blk < 512)       { feat = x2; C = 64;  S = 128; fbase = 0;     pair0 = blk * 2; }
    else if (blk < 1792) { feat = x4; C = 160; S = 64;  fbase = 8192;  pair0 = (blk - 512) * 2; }
    else                 { feat = x6; C = 192; S = 32;  fbase = 28672; pair0 = (blk - 1792) * 2; }

    const int tid  = threadIdx.x;
    const int pair = pair0 + (tid >> 7);   // uniform within each wave
    const int bin  = tid & 127;            // i*8 + j
    const int c    = pair % C;
    const int b    = pair / C;
    const int j = bin & 7;
    const int i = bin >> 3;

    const float* bx = box + b * 4;
    float x = bx[0], y = bx[1], wd = bx[2], ht = bx[3];
    float Sf = (float)S;
    // bit-exact vs np: 0.5*w exact (pow2), fma(x -/+ 0.5w) single-round equals
    // np's x + (-0.5w) since the product is exact; *2^k exact; trunc>=0==floor
    int x1 = (int)(clamp01(x - 0.5f * wd) * Sf);
    int y1 = (int)(clamp01(y - 0.5f * ht) * Sf);
    int x2i = (int)(clamp01(x + 0.5f * wd) * Sf);
    int y2i = (int)(clamp01(y + 0.5f * ht) * Sf);
    x2i = min(x2i, S - 1);
    y2i = min(y2i, S - 1);
    int h = y2i - y1 + 1;
    int w = x2i - x1 + 1;

    int rs = y1 + (i * h) / 16;
    int re = y1 + ((i + 1) * h + 15) / 16;   // ceil
    int cs = x1 + (j * w) / 8;
    int ce = x1 + ((j + 1) * w + 7) / 8;     // ceil

    const float* fp = feat + ((size_t)(b * C + c)) * S * S;
    float m = -INFINITY;
    for (int r = rs; r < re; ++r) {
        const float* row = fp + r * S;
        int cc = cs;
        // 4-wide: independent loads -> 4x memory-level parallelism on the
        // serial fmax chain.
        for (; cc + 3 < ce; cc += 4) {
            float a0 = row[cc + 0];
            float a1 = row[cc + 1];
            float a2 = row[cc + 2];
            float a3 = row[cc + 3];
            m = fmaxf(m, fmaxf(fmaxf(a0, a1), fmaxf(a2, a3)));
        }
        for (; cc < ce; ++cc) m = fmaxf(m, row[cc]);
    }
    // f-major store: f = fbase + c*128 + bin
    rois[((size_t)(fbase + c * 128 + bin)) * 16 + b] = m;
}

// grid (NCHUNK, 7); block 256 = 4 waves. Lane layout: half = lane>>5 picks one
// of 2 f-rows per load, h0 = (lane&31)*4 -> float4 of h-cols. A wave load is
// 1 KB contiguous (two full 512 B f-rows of Wh). With f-major rois, staging is
// a contiguous 32 KB float4 block copy. LDS fragment reads are uniform-address
// broadcasts (bank-conflict-free, confirmed SQ_LDS_BANK_CONFLICT=0).
__global__ __launch_bounds__(256) void matmul_part(const float* __restrict__ rois,
                                                   const float* __restrict__ Wh,
                                                   float* __restrict__ partial) {
    __shared__ float rs_[FC * 16];   // [f_local][b] layout, 32 KB (reused for reduce)
    const int cid = blockIdx.x;
    const int k = blockIdx.y;
    const int f0 = cid * FC;
    const int tid = threadIdx.x;

    // stage rois chunk: contiguous copy, coalesced float4 both sides
    {
        const float4* src = (const float4*)(rois + (size_t)f0 * 16);
        float4* dst = (float4*)rs_;
        for (int idx = tid; idx < FC * 16 / 4; idx += 256) dst[idx] = src[idx];
    }
    __syncthreads();

    const int w    = tid >> 6;          // wave 0..3
    const int l    = tid & 63;
    const int half = l >> 5;            // which of 2 f-rows this lane loads
    const int h0   = (l & 31) * 4;      // 4 h columns per lane

    const float* wp = Wh + ((size_t)k * F_TOT + f0 + 2 * w + half) * 128 + h0;
    int fb = ((2 * w + half) << 4);     // rs_ float offset = fl*16

    float4 acc[16];
#pragma unroll
    for (int b = 0; b < 16; ++b) acc[b] = make_float4(0.f, 0.f, 0.f, 0.f);

#pragma unroll 4
    for (int it = 0; it < FC / 8; ++it) {
        const vf4 wv = __builtin_nontemporal_load((const vf4*)wp);
        wp += 8 * 128;                  // 8 f-rows ahead
        const float* rp = rs_ + fb;
        fb += 128;                      // 8 fl * 16 b
#pragma unroll
        for (int q = 0; q < 4; ++q) {
            const float4 rv = *(const float4*)(rp + q * 4);
            acc[q*4+0].x += rv.x * wv.x; acc[q*4+0].y += rv.x * wv.y;
            acc[q*4+0].z += rv.x * wv.z; acc[q*4+0].w += rv.x * wv.w;
            acc[q*4+1].x += rv.y * wv.x; acc[q*4+1].y += rv.y * wv.y;
            acc[q*4+1].z += rv.y * wv.z; acc[q*4+1].w += rv.y * wv.w;
            acc[q*4+2].x += rv.z * wv.x; acc[q*4+2].y += rv.z * wv.y;
            acc[q*4+2].z += rv.z * wv.z; acc[q*4+2].w += rv.z * wv.w;
            acc[q*4+3].x += rv.w * wv.x; acc[q*4+3].y += rv.w * wv.y;
            acc[q*4+3].z += rv.w * wv.z; acc[q*4+3].w += rv.w * wv.w;
        }
    }

    // Reduce 8 partials (4 waves x 2 halves) -> partial[k][cid][b][h].
    // Round A: half0 lanes write; Round B: half1 lanes RMW-add; Round C: sum 4 waves.
    __syncthreads();                    // everyone done reading rs_
    float* red = rs_;                   // reuse 8192 floats = [w][b*128+h]
    if (half == 0) {
#pragma unroll
        for (int b = 0; b < 16; ++b)
            *(float4*)(red + w * 2048 + b * 128 + h0) = acc[b];
    }
    __syncthreads();
    if (half == 1) {
#pragma unroll
        for (int b = 0; b < 16; ++b) {
            float4* p = (float4*)(red + w * 2048 + b * 128 + h0);
            float4 t = *p;
            t.x += acc[b].x; t.y += acc[b].y; t.z += acc[b].z; t.w += acc[b].w;
            *p = t;
        }
    }
    __syncthreads();

    float* op = partial + ((size_t)(k * NCHUNK + cid)) * (B * 128);
    for (int idx = tid; idx < 2048; idx += 256) {
        op[idx] = red[idx] + red[idx + 2048] + red[idx + 4096] + red[idx + 6144];
    }
}

// Fused split-K reduce + bias + per-k head. One block per (k, b): 112 blocks.
// k=0 -> o1 (38 outs) + box passthrough; k=1 -> o2 (25); k=2..6 -> od[k-2] (35).
// All out columns are disjoint across k, so blocks write independently.
__global__ __launch_bounds__(512) void tail_kernel(const float* __restrict__ partial,
                                                   const float* __restrict__ bh,
                                                   const float* __restrict__ box,
                                                   const float* __restrict__ Wp, const float* __restrict__ bp,
                                                   const float* __restrict__ Wa, const float* __restrict__ ba,
                                                   const float* __restrict__ Wd, const float* __restrict__ bd,
                                                   float* __restrict__ out) {
    __shared__ float red[512];
    __shared__ float hs[128];
    const int k = blockIdx.x >> 4;
    const int b = blockIdx.x & 15;
    const int tid = threadIdx.x;

    // --- split-K reduce: thread (h, q) sums cids q*26 .. q*26+25 ---
    {
        const int h = tid & 127;
        const int q = tid >> 7;         // 0..3
        const float* pp = partial + (size_t)k * NCHUNK * (B * 128) + b * 128 + h
                        + (size_t)(q * 26) * (B * 128);
        float s = 0.f;
#pragma unroll
        for (int cid = 0; cid < 26; ++cid) s += pp[(size_t)cid * (B * 128)];
        red[tid] = s;
    }
    __syncthreads();
    if (tid < 128) {
        hs[tid] = red[tid] + red[tid + 128] + red[tid + 256] + red[tid + 384]
                + bh[k * 128 + tid];
    }
    __syncthreads();

    // --- head for this k: out_o = bias_o + dot(hs, W[:,o]) ---
    // thread = o*8 + p; lane-group p sums h = p*16 .. p*16+15, xor-tree over 8.
    const int o = tid >> 3;
    const int p = tid & 7;
    const int n_out = (k == 0) ? 38 : (k == 1) ? 25 : 35;
    float v = 0.f;
    if (o < n_out) {
        const float* Wc;
        int ld;
        if (k == 0)      { Wc = Wp; ld = 38; }
        else if (k == 1) { Wc = Wa; ld = 25; }
        else             { Wc = Wd + (size_t)(k - 2) * 128 * 35; ld = 35; }
        const int hbase = p * 16;
#pragma unroll
        for (int hh = 0; hh < 16; ++hh) {
            const int h = hbase + hh;
            v += hs[h] * Wc[h * ld + o];
        }
    }
    v += __shfl_xor(v, 1, 8);
    v += __shfl_xor(v, 2, 8);
    v += __shfl_xor(v, 4, 8);
    if (p == 0 && o < n_out) {
        float bias;
        int off;
        if (k == 0)      { bias = bp[o]; off = 4 + o; }
        else if (k == 1) { bias = ba[o]; off = 42 + o; }
        else             { bias = bd[(k - 2) * 35 + o]; off = 67 + (k - 2) * 35 + o; }
        out[b * 242 + off] = bias + v;
    }
    if (k == 0 && tid >= 504) {
        const int j = tid - 504;
        if (j < 4) out[b * 242 + j] = box[b * 4 + j];
    }
}

extern "C" void kernel_launch(void* const* d_in, const int* in_sizes, int n_in,
                              void* d_out, int out_size, void* d_ws, size_t ws_size,
                              hipStream_t stream) {
    const float* box = (const float*)d_in[0];
    const float* x2  = (const float*)d_in[1];
    const float* x4  = (const float*)d_in[2];
    const float* x6  = (const float*)d_in[3];
    const float* Wh  = (const float*)d_in[4];
    const float* bh  = (const float*)d_in[5];
    const float* Wp  = (const float*)d_in[6];
    const float* bp  = (const float*)d_in[7];
    const float* Wa  = (const float*)d_in[8];
    const float* ba  = (const float*)d_in[9];
    const float* Wd  = (const float*)d_in[10];
    const float* bd  = (const float*)d_in[11];
    float* out = (float*)d_out;

    float* ws = (float*)d_ws;
    float* rois    = ws;                      // 3,407,872 f  ([f][b] F-MAJOR)
    float* partial = ws + (size_t)B * F_TOT;  // 1,490,944 f
    (void)ws_size;

    roi_all<<<3328, 256, 0, stream>>>(x2, x4, x6, box, rois);
    matmul_part<<<dim3(NCHUNK, 7), 256, 0, stream>>>(rois, Wh, partial);
    tail_kernel<<<112, 512, 0, stream>>>(partial, bh, box, Wp, bp, Wa, ba, Wd, bd, out);
}